// Round 3
// baseline (399.419 us; speedup 1.0000x reference)
//
#include <hip/hip_runtime.h>

// ---------------------------------------------------------------------------
// IPLS partial_fit, algebraically restructured.
//
// Identities (exact in exact arithmetic):
//   xc0 = r*(x - mu),  r = n/(n+1);  mu_new = x - xc0
//   wz = Wz[i] + u*xc  -> dot(xc,wz) = a + u*s ;  |wz|^2 = w2 + 2ua + u^2 s
//   cz = Cz[i] + t*yc  -> dot(yc,cz) = ay + t*sy; |cz|^2 = c2 + 2t*ay + t^2 sy
//   xc_{i+1} = (1-t^2) xc_i - t P[i]  => xc_i lives in span{xc0, P[j<i]}
//   yc_{i+1} = (1-g t) yc_i - g Cz[i] => yc_i lives in span{yc0, Cz[j<i]}
// The 64-step scan scalars need only the Grams:
//   PW=P@Wz^T, PP=P@P^T, XW=Wz@xc0, XP=P@xc0, W2=diag(Wz@Wz^T), s0=|xc0|^2
//   CC=Cz@Cz^T, YC=Cz@yc0, sy0=|yc0|^2
// and the big outputs need only per-column recurrences driven by (u1,t2,g):
//   Wz_new[i][c] = Wz[i][c] + u1_i*xc ; pn = P[i][c] + t2_i*xc ; xc -= t2_i*pn
//   czn = Cz[i][c] + t2_i*yc ; yc -= g_i*czn
//
// Pipeline (6 launches):
//   gram_partial(X) : prep fused (computes+stores xc0), partial Grams
//   gram_partial(Y) : same for y-side
//   gram_reduce_all : finalize + transpose Grams into ws
//   recursion       : 1 wave, 64 scalar steps -> u/tss/bz + (u1,t2,g)
//   expand_y        : Cz_new + mu_y fixup
//   expand_x        : Wz_new, P_new + mu_x fixup (overwrites partial scratch)
// ---------------------------------------------------------------------------

#define NF 131072
#define NT 2048
#define NL 64

#define PSIZE 8385      // 4096 PW + 4096 PP + 64 XW + 64 XP + 64 W2 + 1 s0
#define NBX 512
#define NBY 16
#define BK 128
#define LDST 68         // k-major LDS stride: 16B-aligned b128 reads, 2-way read /
                        // 4-way write conflicts with the row-remapped staging

// d_out offsets (floats), reference return order
#define O_MUX 0
#define O_MUY 131072
#define O_U   133120
#define O_WZ  133184
#define O_CZ  8521792
#define O_TSS 8652864
#define O_BZ  8652928
#define O_P   8652992

// d_ws offsets (floats) -- ~17k floats (~68 KB)
#define W_FINX 0
#define W_FINY 8385
#define W_COEF 16770    // u1[64] | t2[64] | g[64]

// ---------------------------------------------------------------------------
// Partial Grams over a K-chunk, with centering fused:
//   v = r*(xs - mus) on this block's chunk (also stored to vout),
//   PW = A@B^T, PP = A@A^T, XW = B@v, XP = A@v, W2 = rowSumSq(B), s0 = v.v
// 256 threads = 4 waves; each wave a k-quarter; 8x8 per-lane output tile.
__global__ __launch_bounds__(256) void gram_partial(
    const float* __restrict__ A, const float* __restrict__ B,
    const float* __restrict__ xs, const float* __restrict__ mus,
    const int* __restrict__ np, int K, int KC,
    float* __restrict__ part, float* __restrict__ vout)
{
    __shared__ float lds[2 * BK * LDST + BK];
    float* ldsA = lds;
    float* ldsB = lds + BK * LDST;
    float* ldsV = lds + 2 * BK * LDST;

    const int t    = threadIdx.x;
    const int w    = t >> 6;
    const int lane = t & 63;
    const int j0   = lane & 56;          // A-row base  {0,8,...,56}
    const int i0   = (lane & 7) << 3;    // B-row base  {0,8,...,56}

    const float nf = (float)(*np);
    const float r  = nf / (nf + 1.f);

    float accPW[8][8], accPP[8][8];
    float accXW[8], accXP[8], accW2[8], accS0 = 0.f;
#pragma unroll
    for (int s = 0; s < 8; ++s) {
        accXW[s] = 0.f; accXP[s] = 0.f; accW2[s] = 0.f;
#pragma unroll
        for (int q = 0; q < 8; ++q) { accPW[s][q] = 0.f; accPP[s][q] = 0.f; }
    }

    const int kbase  = (int)blockIdx.x * KC;
    const int ntiles = KC / BK;
    const int c4     = ((t >> 3) & 31) << 2;   // k-subgroup (fixed per thread)
    const int rlow   = t & 7;                  // row low bits (fixed per thread)

    for (int tile = 0; tile < ntiles; ++tile) {
        const int k0 = kbase + tile * BK;
        if (tile) __syncthreads();
        // stage k-major lds[kk][row]; 8 consecutive lanes write 8 DIFFERENT
        // rows -> write banks 16-distinct (4-way, ~free) instead of 16-way.
#pragma unroll
        for (int m = 0; m < 8; ++m) {
            int row = rlow | (m << 3);
            const float4 av = *(const float4*)(A + (size_t)row * K + (k0 + c4));
            const float4 bv = *(const float4*)(B + (size_t)row * K + (k0 + c4));
            ldsA[(c4 + 0) * LDST + row] = av.x;
            ldsA[(c4 + 1) * LDST + row] = av.y;
            ldsA[(c4 + 2) * LDST + row] = av.z;
            ldsA[(c4 + 3) * LDST + row] = av.w;
            ldsB[(c4 + 0) * LDST + row] = bv.x;
            ldsB[(c4 + 1) * LDST + row] = bv.y;
            ldsB[(c4 + 2) * LDST + row] = bv.z;
            ldsB[(c4 + 3) * LDST + row] = bv.w;
        }
        if (t < BK) {
            float val = r * (xs[k0 + t] - mus[k0 + t]);   // centered sample
            ldsV[t] = val;
            vout[k0 + t] = val;                            // stash for expand
        }
        __syncthreads();

        const int kend = w * 32 + 32;
        for (int kk = w * 32; kk < kend; ++kk) {
            const float* bA = ldsA + kk * LDST;
            const float* bB = ldsB + kk * LDST;
            float4 a0 = *(const float4*)(bA + j0);
            float4 a1 = *(const float4*)(bA + j0 + 4);
            float4 b0 = *(const float4*)(bB + i0);
            float4 b1 = *(const float4*)(bB + i0 + 4);
            float4 c0 = *(const float4*)(bA + i0);
            float4 c1 = *(const float4*)(bA + i0 + 4);
            float aj[8] = {a0.x,a0.y,a0.z,a0.w,a1.x,a1.y,a1.z,a1.w};
            float bi[8] = {b0.x,b0.y,b0.z,b0.w,b1.x,b1.y,b1.z,b1.w};
            float ci[8] = {c0.x,c0.y,c0.z,c0.w,c1.x,c1.y,c1.z,c1.w};
#pragma unroll
            for (int s = 0; s < 8; ++s)
#pragma unroll
                for (int q = 0; q < 8; ++q) {
                    accPW[s][q] = fmaf(aj[s], bi[q], accPW[s][q]);
                    accPP[s][q] = fmaf(aj[s], ci[q], accPP[s][q]);
                }
            float vv = ldsV[kk];
            if (j0 == 0) {
#pragma unroll
                for (int q = 0; q < 8; ++q) accXW[q] = fmaf(vv, bi[q], accXW[q]);
            }
            if (j0 == 8) {
#pragma unroll
                for (int q = 0; q < 8; ++q) accW2[q] = fmaf(bi[q], bi[q], accW2[q]);
            }
            if (i0 == 0) {
#pragma unroll
                for (int s = 0; s < 8; ++s) accXP[s] = fmaf(vv, aj[s], accXP[s]);
            }
            if (lane == 16) accS0 = fmaf(vv, vv, accS0);
        }
    }
    __syncthreads();

    float* red = lds;                         // reuse staging LDS (16384<17536)
    float* po  = part + (size_t)blockIdx.x * PSIZE;
    // --- PW phase
#pragma unroll
    for (int s = 0; s < 8; ++s)
#pragma unroll
        for (int q = 0; q < 8; ++q)
            red[w * 4096 + (j0 + s) * 64 + (i0 + q)] = accPW[s][q];
    __syncthreads();
    for (int o = t; o < 4096; o += 256)
        po[o] = red[o] + red[4096 + o] + red[8192 + o] + red[12288 + o];
    __syncthreads();
    // --- PP phase
#pragma unroll
    for (int s = 0; s < 8; ++s)
#pragma unroll
        for (int q = 0; q < 8; ++q)
            red[w * 4096 + (j0 + s) * 64 + (i0 + q)] = accPP[s][q];
    __syncthreads();
    for (int o = t; o < 4096; o += 256)
        po[4096 + o] = red[o] + red[4096 + o] + red[8192 + o] + red[12288 + o];
    __syncthreads();
    // --- extras: XW[64] | XP[64] | W2[64] | s0
    if (j0 == 0) {
#pragma unroll
        for (int q = 0; q < 8; ++q) red[w * 193 + (i0 + q)] = accXW[q];
    }
    if (i0 == 0) {
#pragma unroll
        for (int s = 0; s < 8; ++s) red[w * 193 + 64 + (j0 + s)] = accXP[s];
    }
    if (j0 == 8) {
#pragma unroll
        for (int q = 0; q < 8; ++q) red[w * 193 + 128 + (i0 + q)] = accW2[q];
    }
    if (lane == 16) red[w * 193 + 192] = accS0;
    __syncthreads();
    for (int o = t; o < 193; o += 256)
        po[8192 + o] = red[o] + red[193 + o] + red[386 + o] + red[579 + o];
}

// Reduce block partials for BOTH gram sets; transpose PW/PP so the recursion
// reads contiguous rows: fin[i*64+j] = G[j][i].  Blocks [0,33)->X, [33,66)->Y.
__global__ __launch_bounds__(256) void gram_reduce_all(
    const float* __restrict__ partX, const float* __restrict__ partY,
    float* __restrict__ finX, float* __restrict__ finY)
{
    int b = blockIdx.x;
    const float* part; float* fin; int nb; int o;
    if (b < 33) { part = partX; fin = finX; nb = NBX; o = b * 256 + threadIdx.x; }
    else        { part = partY; fin = finY; nb = NBY; o = (b - 33) * 256 + threadIdx.x; }
    if (o >= PSIZE) return;
    float s = 0.f;
    for (int k = 0; k < nb; ++k) s += part[(size_t)k * PSIZE + o];
    if (o < 4096) {
        int j = o >> 6, i = o & 63;
        fin[(i << 6) + j] = s;
    } else if (o < 8192) {
        int q = o - 4096;
        int j = q >> 6, i = q & 63;
        fin[4096 + (i << 6) + j] = s;
    } else {
        fin[o] = s;
    }
}

// ---------------------------------------------------------------------------
// 64-step scalar recursion. One wave; lane j carries beta_j / delta_j.
// Emits u/tss/bz outputs and the (u1,t2,g) vectors that drive the expands.
__global__ __launch_bounds__(64) void recursion(
    const float* __restrict__ finX, const float* __restrict__ finY,
    const float* __restrict__ u_in, const float* __restrict__ tss_in,
    const float* __restrict__ bz_in,
    float* __restrict__ out_u, float* __restrict__ out_tss, float* __restrict__ out_bz,
    float* __restrict__ coef)
{
    const int lane = threadIdx.x;
    const float* PWt = finX;            // [i*64+j] = dot(P_j, Wz_i)
    const float* PPt = finX + 4096;     // [i*64+j] = dot(P_j, P_i)
    const float* XW  = finX + 8192;
    const float* XP  = finX + 8256;
    const float* W2  = finX + 8320;
    const float* CCt = finY;            // [i*64+j] = dot(Cz_j, Cz_i)
    const float* YC  = finY + 8192;

    float beta = 0.f, delta = 0.f;
    float alpha = 1.f, gamma = 1.f;
    float s  = finX[8384];              // |xc0|^2
    float sy = finY[8384];              // |yc0|^2

    float rPW = PWt[lane], rPP = PPt[lane], rCC = CCt[lane];

    for (int i = 0; i < NL; ++i) {
        int inext = (i + 1) & 63;
        float nPW = PWt[inext * 64 + lane];
        float nPP = PPt[inext * 64 + lane];
        float nCC = CCt[inext * 64 + lane];

        float v0 = beta * rPW, v1 = beta * rPP, v2 = delta * rCC;
#pragma unroll
        for (int off = 32; off; off >>= 1) {
            v0 += __shfl_xor(v0, off);
            v1 += __shfl_xor(v1, off);
            v2 += __shfl_xor(v2, off);
        }
        float a  = alpha * XW[i] + v0;    // dot(xc_i, Wz[i])
        float d  = alpha * XP[i] + v1;    // dot(xc_i, P[i])
        float ay = gamma * YC[i] + v2;    // dot(yc_i, Cz[i])
        float ppii = __shfl(rPP, i);      // |P[i]|^2
        float c2   = __shfl(rCC, i);      // |Cz[i]|^2
        float w2   = W2[i];
        float u0 = u_in[i], tss0 = tss_in[i], bzi = bz_in[i];

        // --- inner pass 1 (input u0)
        float den1 = sqrtf(fmaxf(w2 + 2.f * u0 * a + u0 * u0 * s, 0.f)) + 1e-7f;
        float tz1  = (a + u0 * s) / den1;
        float tss1 = tss0 + tz1 * tz1;
        float t1   = tz1 / sqrtf(tss1);
        float cn1  = sqrtf(fmaxf(c2 + 2.f * t1 * ay + t1 * t1 * sy, 0.f));
        float u1   = (ay + t1 * sy) / cn1;
        // --- inner pass 2 (input u1)
        float den2  = sqrtf(fmaxf(w2 + 2.f * u1 * a + u1 * u1 * s, 0.f)) + 1e-7f;
        float tz2   = (a + u1 * s) / den2;
        float tss2  = tss0 + tz2 * tz2;
        float st2   = sqrtf(tss2);
        float t2    = tz2 / st2;
        float cn2sq = fmaxf(c2 + 2.f * t2 * ay + t2 * t2 * sy, 0.f);
        float cn2   = sqrtf(cn2sq);
        float u2    = (ay + t2 * sy) / cn2;
        float bzo   = bzi + u2 * tz2;
        float b     = bzo / st2;
        float g     = b * t2 / cn2;

        if (lane == 0) {
            out_u[i]   = u2;
            out_tss[i] = tss2;
            out_bz[i]  = bzo;
            coef[i]            = u1;   // Wz_new[i] = Wz[i] + u1*xc_i
            coef[NL + i]       = t2;   // P/Cz updates + deflation
            coef[2 * NL + i]   = g;    // y deflation
        }

        // --- deflate (scalar state + lane-distributed basis coefficients)
        float f  = 1.f - t2 * t2;
        float fy = 1.f - g * t2;
        s  = f * f * s - 2.f * f * t2 * d + t2 * t2 * ppii;
        sy = sy - 2.f * g * (ay + t2 * sy) + g * g * cn2sq;
        beta  *= f;  if (lane == i) beta  = -t2;
        delta *= fy; if (lane == i) delta = -g;
        alpha *= f;
        gamma *= fy;

        rPW = nPW; rPP = nPP; rCC = nCC;
    }
}

// ---------------------------------------------------------------------------
// Per-column recurrence: regenerates xc_i on the fly — no coefficient matrix,
// no LDS tile, pure streaming.  Also recovers mu_x in place (mu = x - xc0).
__global__ __launch_bounds__(128) void expand_x(
    const float* __restrict__ P, const float* __restrict__ Wz,
    const float* __restrict__ x, const float* __restrict__ coef,
    float* __restrict__ xc0_mux,     // in: xc0 chunk, out: mu_x (same slot)
    float* __restrict__ outW, float* __restrict__ outP)
{
    __shared__ float cu1[NL], ct2[NL];
    const int t = threadIdx.x;
    if (t < NL) { cu1[t] = coef[t]; ct2[t] = coef[NL + t]; }
    const int c = ((int)blockIdx.x * 128 + t) << 2;
    float4 xc = *(const float4*)(xc0_mux + c);
    float4 xv = *(const float4*)(x + c);
    float4 mu;
    mu.x = xv.x - xc.x; mu.y = xv.y - xc.y;
    mu.z = xv.z - xc.z; mu.w = xv.w - xc.w;
    *(float4*)(xc0_mux + c) = mu;
    __syncthreads();
#pragma unroll 4
    for (int i = 0; i < NL; ++i) {
        size_t off = (size_t)i * NF + c;
        float4 wv = *(const float4*)(Wz + off);
        float4 pv = *(const float4*)(P + off);
        float u1 = cu1[i], t2 = ct2[i];
        wv.x = fmaf(u1, xc.x, wv.x); wv.y = fmaf(u1, xc.y, wv.y);
        wv.z = fmaf(u1, xc.z, wv.z); wv.w = fmaf(u1, xc.w, wv.w);
        pv.x = fmaf(t2, xc.x, pv.x); pv.y = fmaf(t2, xc.y, pv.y);
        pv.z = fmaf(t2, xc.z, pv.z); pv.w = fmaf(t2, xc.w, pv.w);
        *(float4*)(outW + off) = wv;
        *(float4*)(outP + off) = pv;
        xc.x = fmaf(-t2, pv.x, xc.x); xc.y = fmaf(-t2, pv.y, xc.y);
        xc.z = fmaf(-t2, pv.z, xc.z); xc.w = fmaf(-t2, pv.w, xc.w);
    }
}

__global__ __launch_bounds__(128) void expand_y(
    const float* __restrict__ Cz, const float* __restrict__ y,
    const float* __restrict__ coef,
    float* __restrict__ yc0_muy,     // in: yc0 chunk, out: mu_y (same slot)
    float* __restrict__ outC)
{
    __shared__ float ct2[NL], cg[NL];
    const int t = threadIdx.x;
    if (t < NL) { ct2[t] = coef[NL + t]; cg[t] = coef[2 * NL + t]; }
    const int c = ((int)blockIdx.x * 128 + t) << 2;
    float4 yc = *(const float4*)(yc0_muy + c);
    float4 yv = *(const float4*)(y + c);
    float4 mu;
    mu.x = yv.x - yc.x; mu.y = yv.y - yc.y;
    mu.z = yv.z - yc.z; mu.w = yv.w - yc.w;
    *(float4*)(yc0_muy + c) = mu;
    __syncthreads();
#pragma unroll 4
    for (int i = 0; i < NL; ++i) {
        size_t off = (size_t)i * NT + c;
        float4 cv = *(const float4*)(Cz + off);
        float t2 = ct2[i], g = cg[i];
        cv.x = fmaf(t2, yc.x, cv.x); cv.y = fmaf(t2, yc.y, cv.y);
        cv.z = fmaf(t2, yc.z, cv.z); cv.w = fmaf(t2, yc.w, cv.w);
        *(float4*)(outC + off) = cv;
        yc.x = fmaf(-g, cv.x, yc.x); yc.y = fmaf(-g, cv.y, yc.y);
        yc.z = fmaf(-g, cv.z, yc.z); yc.w = fmaf(-g, cv.w, yc.w);
    }
}

// ---------------------------------------------------------------------------
extern "C" void kernel_launch(void* const* d_in, const int* in_sizes, int n_in,
                              void* d_out, int out_size, void* d_ws, size_t ws_size,
                              hipStream_t stream)
{
    (void)in_sizes; (void)n_in; (void)out_size; (void)ws_size;

    const float* x    = (const float*)d_in[0];
    const float* y    = (const float*)d_in[1];
    const float* mu_x = (const float*)d_in[2];
    const float* mu_y = (const float*)d_in[3];
    const float* u    = (const float*)d_in[4];
    const float* Wz   = (const float*)d_in[5];
    const float* Cz   = (const float*)d_in[6];
    const float* tss  = (const float*)d_in[7];
    const float* bz   = (const float*)d_in[8];
    const float* P    = (const float*)d_in[9];
    const int*   n    = (const int*)d_in[10];

    float* out = (float*)d_out;
    float* ws  = (float*)d_ws;

    float* xc0   = out + O_MUX;             // stashed in mu_x slot until expand_x
    float* yc0   = out + O_MUY;
    float* partX = out + O_P;               // scratch inside P_new output region
    float* partY = partX + (size_t)NBX * PSIZE;  // 4.43M floats < 8.39M  OK
    float* finX  = ws + W_FINX;
    float* finY  = ws + W_FINY;
    float* coef  = ws + W_COEF;

    gram_partial<<<NBX, 256, 0, stream>>>(P,  Wz, x, mu_x, n, NF, NF / NBX,
                                          partX, xc0);
    gram_partial<<<NBY, 256, 0, stream>>>(Cz, Cz, y, mu_y, n, NT, NT / NBY,
                                          partY, yc0);

    gram_reduce_all<<<66, 256, 0, stream>>>(partX, partY, finX, finY);

    recursion<<<1, 64, 0, stream>>>(finX, finY, u, tss, bz,
                                    out + O_U, out + O_TSS, out + O_BZ, coef);

    expand_y<<<NT / 512, 128, 0, stream>>>(Cz, y, coef, yc0, out + O_CZ);
    expand_x<<<NF / 512, 128, 0, stream>>>(P, Wz, x, coef, xc0,
                                           out + O_WZ, out + O_P);
}

// Round 5
// 261.098 us; speedup vs baseline: 1.5298x; 1.5298x over previous
//
#include <hip/hip_runtime.h>

// ---------------------------------------------------------------------------
// IPLS partial_fit, algebraically restructured.
//
// Identities (exact in exact arithmetic):
//   xc0 = r*(x - mu),  r = n/(n+1);  mu_new = x - xc0
//   wz = Wz[i] + u*xc  -> dot(xc,wz) = a + u*s ;  |wz|^2 = w2 + 2ua + u^2 s
//   cz = Cz[i] + t*yc  -> dot(yc,cz) = ay + t*sy; |cz|^2 = c2 + 2t*ay + t^2 sy
//   xc_{i+1} = (1-t^2) xc_i - t P[i]  => xc_i lives in span{xc0, P[j<i]}
//   yc_{i+1} = (1-g t) yc_i - g Cz[i] => yc_i lives in span{yc0, Cz[j<i]}
// The 64-step scan scalars need only the Grams:
//   PW=P@Wz^T, PP=P@P^T, XW=Wz@xc0, XP=P@xc0, W2=diag(Wz@Wz^T), s0=|xc0|^2
//   CC=Cz@Cz^T, YC=Cz@yc0, sy0=|yc0|^2
// and the big outputs need only per-column recurrences driven by (u1,t2,g).
//
// Pipeline (5 launches):
//   gram_partial : X blocks [0,512) + Y blocks [512,528), centering fused
//   gram_reduceA : 1056 blocks, k-split partial reduction X: 512 -> 32
//   gram_reduceB : finalize (32 -> 1 X, 16 -> 1 Y) + transpose into ws
//   recursion    : LDS-staged; 1 wave, 64 scalar steps -> u/tss/bz + coef
//   expand       : X blocks [0,256) Wz/P + mu_x, Y blocks [256,260) Cz + mu_y
// ---------------------------------------------------------------------------

#define NF 131072
#define NT 2048
#define NL 64

#define PSIZE 8385      // 4096 PW + 4096 PP + 64 XW + 64 XP + 64 W2 + 1 s0
#define NBX 512
#define NBY 16
#define NMID 32         // stage-A output groups (512/16)
#define REDK 16         // partials summed per stage-A block
#define BK 128
#define LDST 68         // k-major LDS stride: 16B-aligned b128 reads
#define NBEX 256        // expand x-blocks (NF/512)
#define NBEY 4          // expand y-blocks (NT/512)

// d_out offsets (floats), reference return order
#define O_MUX 0
#define O_MUY 131072
#define O_U   133120
#define O_WZ  133184
#define O_CZ  8521792
#define O_TSS 8652864
#define O_BZ  8652928
#define O_P   8652992

// d_ws offsets (floats)
#define W_FINX 0
#define W_FINY 8385
#define W_COEF 16770    // u1[64] | t2[64] | g[64]

// ---------------------------------------------------------------------------
// Partial Grams over a K-chunk, with centering fused:
//   v = r*(xs - mus) on this block's chunk (also stored to vout),
//   PW = A@B^T, PP = A@A^T, XW = B@v, XP = A@v, W2 = rowSumSq(B), s0 = v.v
// Blocks [0,NBX): A=P, B=Wz, K=NF.  Blocks [NBX,NBX+NBY): A=B=Cz, K=NT.
// 256 threads = 4 waves; each wave a k-quarter; 8x8 per-lane output tile.
__global__ __launch_bounds__(256) void gram_partial(
    const float* __restrict__ PX, const float* __restrict__ WzX,
    const float* __restrict__ xsX, const float* __restrict__ musX,
    const float* __restrict__ CzY, const float* __restrict__ ysY,
    const float* __restrict__ musY, const int* __restrict__ np,
    float* __restrict__ partX, float* __restrict__ voutX,
    float* __restrict__ partY, float* __restrict__ voutY)
{
    __shared__ float lds[2 * BK * LDST + BK];
    float* ldsA = lds;
    float* ldsB = lds + BK * LDST;
    float* ldsV = lds + 2 * BK * LDST;

    const bool isX = (int)blockIdx.x < NBX;
    const float* A   = isX ? PX   : CzY;
    const float* B   = isX ? WzX  : CzY;
    const float* xs  = isX ? xsX  : ysY;
    const float* mus = isX ? musX : musY;
    float* part      = isX ? partX : partY;
    float* vout      = isX ? voutX : voutY;
    const int K   = isX ? NF : NT;
    const int KC  = isX ? (NF / NBX) : (NT / NBY);   // 256 : 128
    const int bid = isX ? (int)blockIdx.x : (int)blockIdx.x - NBX;

    const int t    = threadIdx.x;
    const int w    = t >> 6;
    const int lane = t & 63;
    const int j0   = lane & 56;          // A-row base  {0,8,...,56}
    const int i0   = (lane & 7) << 3;    // B-row base  {0,8,...,56}

    const float nf = (float)(*np);
    const float r  = nf / (nf + 1.f);

    float accPW[8][8], accPP[8][8];
    float accXW[8], accXP[8], accW2[8], accS0 = 0.f;
#pragma unroll
    for (int s = 0; s < 8; ++s) {
        accXW[s] = 0.f; accXP[s] = 0.f; accW2[s] = 0.f;
#pragma unroll
        for (int q = 0; q < 8; ++q) { accPW[s][q] = 0.f; accPP[s][q] = 0.f; }
    }

    const int kbase  = bid * KC;
    const int ntiles = KC / BK;                // 2 (X) or 1 (Y)
    const int c4     = ((t >> 3) & 31) << 2;   // k-subgroup (fixed per thread)
    const int rlow   = t & 7;                  // row low bits (fixed per thread)

    for (int tile = 0; tile < ntiles; ++tile) {
        const int k0 = kbase + tile * BK;
        if (tile) __syncthreads();
        // stage k-major lds[kk][row]; 8 consecutive lanes write 8 DIFFERENT
        // rows -> 4-way write conflict (~free) instead of 16-way.
#pragma unroll
        for (int m = 0; m < 8; ++m) {
            int row = rlow | (m << 3);
            const float4 av = *(const float4*)(A + (size_t)row * K + (k0 + c4));
            const float4 bv = *(const float4*)(B + (size_t)row * K + (k0 + c4));
            ldsA[(c4 + 0) * LDST + row] = av.x;
            ldsA[(c4 + 1) * LDST + row] = av.y;
            ldsA[(c4 + 2) * LDST + row] = av.z;
            ldsA[(c4 + 3) * LDST + row] = av.w;
            ldsB[(c4 + 0) * LDST + row] = bv.x;
            ldsB[(c4 + 1) * LDST + row] = bv.y;
            ldsB[(c4 + 2) * LDST + row] = bv.z;
            ldsB[(c4 + 3) * LDST + row] = bv.w;
        }
        if (t < BK) {
            float val = r * (xs[k0 + t] - mus[k0 + t]);   // centered sample
            ldsV[t] = val;
            vout[k0 + t] = val;                            // stash for expand
        }
        __syncthreads();

        const int kend = w * 32 + 32;
        for (int kk = w * 32; kk < kend; ++kk) {
            const float* bA = ldsA + kk * LDST;
            const float* bB = ldsB + kk * LDST;
            float4 a0 = *(const float4*)(bA + j0);
            float4 a1 = *(const float4*)(bA + j0 + 4);
            float4 b0 = *(const float4*)(bB + i0);
            float4 b1 = *(const float4*)(bB + i0 + 4);
            float4 c0 = *(const float4*)(bA + i0);
            float4 c1 = *(const float4*)(bA + i0 + 4);
            float aj[8] = {a0.x,a0.y,a0.z,a0.w,a1.x,a1.y,a1.z,a1.w};
            float bi[8] = {b0.x,b0.y,b0.z,b0.w,b1.x,b1.y,b1.z,b1.w};
            float ci[8] = {c0.x,c0.y,c0.z,c0.w,c1.x,c1.y,c1.z,c1.w};
#pragma unroll
            for (int s = 0; s < 8; ++s)
#pragma unroll
                for (int q = 0; q < 8; ++q) {
                    accPW[s][q] = fmaf(aj[s], bi[q], accPW[s][q]);
                    accPP[s][q] = fmaf(aj[s], ci[q], accPP[s][q]);
                }
            float vv = ldsV[kk];
            if (j0 == 0) {
#pragma unroll
                for (int q = 0; q < 8; ++q) accXW[q] = fmaf(vv, bi[q], accXW[q]);
            }
            if (j0 == 8) {
#pragma unroll
                for (int q = 0; q < 8; ++q) accW2[q] = fmaf(bi[q], bi[q], accW2[q]);
            }
            if (i0 == 0) {
#pragma unroll
                for (int s = 0; s < 8; ++s) accXP[s] = fmaf(vv, aj[s], accXP[s]);
            }
            if (lane == 16) accS0 = fmaf(vv, vv, accS0);
        }
    }
    __syncthreads();

    float* red = lds;                         // reuse staging LDS
    float* po  = part + (size_t)bid * PSIZE;
    // --- PW phase
#pragma unroll
    for (int s = 0; s < 8; ++s)
#pragma unroll
        for (int q = 0; q < 8; ++q)
            red[w * 4096 + (j0 + s) * 64 + (i0 + q)] = accPW[s][q];
    __syncthreads();
    for (int o = t; o < 4096; o += 256)
        po[o] = red[o] + red[4096 + o] + red[8192 + o] + red[12288 + o];
    __syncthreads();
    // --- PP phase
#pragma unroll
    for (int s = 0; s < 8; ++s)
#pragma unroll
        for (int q = 0; q < 8; ++q)
            red[w * 4096 + (j0 + s) * 64 + (i0 + q)] = accPP[s][q];
    __syncthreads();
    for (int o = t; o < 4096; o += 256)
        po[4096 + o] = red[o] + red[4096 + o] + red[8192 + o] + red[12288 + o];
    __syncthreads();
    // --- extras: XW[64] | XP[64] | W2[64] | s0
    if (j0 == 0) {
#pragma unroll
        for (int q = 0; q < 8; ++q) red[w * 193 + (i0 + q)] = accXW[q];
    }
    if (i0 == 0) {
#pragma unroll
        for (int s = 0; s < 8; ++s) red[w * 193 + 64 + (j0 + s)] = accXP[s];
    }
    if (j0 == 8) {
#pragma unroll
        for (int q = 0; q < 8; ++q) red[w * 193 + 128 + (i0 + q)] = accW2[q];
    }
    if (lane == 16) red[w * 193 + 192] = accS0;
    __syncthreads();
    for (int o = t; o < 193; o += 256)
        po[8192 + o] = red[o] + red[193 + o] + red[386 + o] + red[579 + o];
}

// ---------------------------------------------------------------------------
// Stage A: k-split reduction 512 -> 32.  Grid 33 x NMID; fully unrolled inner
// sum of REDK coalesced strided loads -> latency covered by 1056 blocks.
__global__ __launch_bounds__(256) void gram_reduceA(
    const float* __restrict__ partX, float* __restrict__ mid)
{
    int ob = (int)blockIdx.x % 33;
    int kb = (int)blockIdx.x / 33;
    int o  = ob * 256 + threadIdx.x;
    if (o >= PSIZE) return;
    const float* p = partX + (size_t)kb * REDK * PSIZE + o;
    float s = 0.f;
#pragma unroll
    for (int k = 0; k < REDK; ++k) s += p[(size_t)k * PSIZE];
    mid[(size_t)kb * PSIZE + o] = s;
}

// Stage B: finalize (X: 32 mids, Y: 16 partials) + transpose PW/PP so the
// recursion reads contiguous rows: fin[i*64+j] = G[j][i]. Blocks [0,33)->X.
__global__ __launch_bounds__(256) void gram_reduceB(
    const float* __restrict__ mid, const float* __restrict__ partY,
    float* __restrict__ finX, float* __restrict__ finY)
{
    int b = blockIdx.x;
    float s = 0.f;
    float* fin; int o;
    if (b < 33) {
        o = b * 256 + threadIdx.x;
        if (o >= PSIZE) return;
        fin = finX;
#pragma unroll
        for (int k = 0; k < NMID; ++k) s += mid[(size_t)k * PSIZE + o];
    } else {
        o = (b - 33) * 256 + threadIdx.x;
        if (o >= PSIZE) return;
        fin = finY;
#pragma unroll
        for (int k = 0; k < NBY; ++k) s += partY[(size_t)k * PSIZE + o];
    }
    if (o < 4096) {
        int j = o >> 6, i = o & 63;
        fin[(i << 6) + j] = s;
    } else if (o < 8192) {
        int q = o - 4096;
        int j = q >> 6, i = q & 63;
        fin[4096 + (i << 6) + j] = s;
    } else {
        fin[o] = s;
    }
}

// ---------------------------------------------------------------------------
// 64-step scalar recursion. 256 threads stage ALL inputs into LDS first
// (kills the per-iteration L3 uniform-load latency), then wave 0 runs the
// serial scan with ~120cy LDS reads. Lane j carries beta_j / delta_j.
__global__ __launch_bounds__(256) void recursion(
    const float* __restrict__ finX, const float* __restrict__ finY,
    const float* __restrict__ u_in, const float* __restrict__ tss_in,
    const float* __restrict__ bz_in,
    float* __restrict__ out_u, float* __restrict__ out_tss, float* __restrict__ out_bz,
    float* __restrict__ coef)
{
    __shared__ float lx[PSIZE];       // PW^T | PP^T | XW | XP | W2 | s0
    __shared__ float ly[PSIZE];       // CC^T | ---- | YC | -- | -- | sy0
    __shared__ float lsc[3 * NL];     // u | tss | bz

    const int t = threadIdx.x;
    for (int o = t; o < PSIZE; o += 256) { lx[o] = finX[o]; ly[o] = finY[o]; }
    if (t < NL) {
        lsc[t]          = u_in[t];
        lsc[NL + t]     = tss_in[t];
        lsc[2 * NL + t] = bz_in[t];
    }
    __syncthreads();
    if (t >= 64) return;
    const int lane = t;

    const float* PWt = lx;
    const float* PPt = lx + 4096;
    const float* XW  = lx + 8192;
    const float* XP  = lx + 8256;
    const float* W2  = lx + 8320;
    const float* CCt = ly;
    const float* YC  = ly + 8192;

    float beta = 0.f, delta = 0.f;
    float alpha = 1.f, gamma = 1.f;
    float s  = lx[8384];              // |xc0|^2
    float sy = ly[8384];              // |yc0|^2

    float rPW = PWt[lane], rPP = PPt[lane], rCC = CCt[lane];

    for (int i = 0; i < NL; ++i) {
        int inext = (i + 1) & 63;
        float nPW = PWt[inext * 64 + lane];
        float nPP = PPt[inext * 64 + lane];
        float nCC = CCt[inext * 64 + lane];

        float v0 = beta * rPW, v1 = beta * rPP, v2 = delta * rCC;
#pragma unroll
        for (int off = 32; off; off >>= 1) {
            v0 += __shfl_xor(v0, off);
            v1 += __shfl_xor(v1, off);
            v2 += __shfl_xor(v2, off);
        }
        float a  = alpha * XW[i] + v0;    // dot(xc_i, Wz[i])
        float d  = alpha * XP[i] + v1;    // dot(xc_i, P[i])
        float ay = gamma * YC[i] + v2;    // dot(yc_i, Cz[i])
        float ppii = __shfl(rPP, i);      // |P[i]|^2
        float c2   = __shfl(rCC, i);      // |Cz[i]|^2
        float w2   = W2[i];
        float u0 = lsc[i], tss0 = lsc[NL + i], bzi = lsc[2 * NL + i];

        // --- inner pass 1 (input u0)
        float den1 = sqrtf(fmaxf(w2 + 2.f * u0 * a + u0 * u0 * s, 0.f)) + 1e-7f;
        float tz1  = (a + u0 * s) / den1;
        float tss1 = tss0 + tz1 * tz1;
        float t1   = tz1 / sqrtf(tss1);
        float cn1  = sqrtf(fmaxf(c2 + 2.f * t1 * ay + t1 * t1 * sy, 0.f));
        float u1   = (ay + t1 * sy) / cn1;
        // --- inner pass 2 (input u1)
        float den2  = sqrtf(fmaxf(w2 + 2.f * u1 * a + u1 * u1 * s, 0.f)) + 1e-7f;
        float tz2   = (a + u1 * s) / den2;
        float tss2  = tss0 + tz2 * tz2;
        float st2   = sqrtf(tss2);
        float t2    = tz2 / st2;
        float cn2sq = fmaxf(c2 + 2.f * t2 * ay + t2 * t2 * sy, 0.f);
        float cn2   = sqrtf(cn2sq);
        float u2    = (ay + t2 * sy) / cn2;
        float bzo   = bzi + u2 * tz2;
        float b     = bzo / st2;
        float g     = b * t2 / cn2;

        if (lane == 0) {
            out_u[i]   = u2;
            out_tss[i] = tss2;
            out_bz[i]  = bzo;
            coef[i]            = u1;   // Wz_new[i] = Wz[i] + u1*xc_i
            coef[NL + i]       = t2;   // P/Cz updates + deflation
            coef[2 * NL + i]   = g;    // y deflation
        }

        // --- deflate (scalar state + lane-distributed basis coefficients)
        float f  = 1.f - t2 * t2;
        float fy = 1.f - g * t2;
        s  = f * f * s - 2.f * f * t2 * d + t2 * t2 * ppii;
        sy = sy - 2.f * g * (ay + t2 * sy) + g * g * cn2sq;
        beta  *= f;  if (lane == i) beta  = -t2;
        delta *= fy; if (lane == i) delta = -g;
        alpha *= f;
        gamma *= fy;

        rPW = nPW; rPP = nPP; rCC = nCC;
    }
}

// ---------------------------------------------------------------------------
// Per-column recurrence: regenerates xc_i / yc_i on the fly — pure streaming.
// Blocks [0,NBEX): Wz_new/P_new + mu_x fixup.  [NBEX,NBEX+NBEY): Cz_new + mu_y.
// unroll 8 lets the compiler hoist address-independent loads ahead of the
// dependent xc/yc chain.
__global__ __launch_bounds__(128) void expand(
    const float* __restrict__ P, const float* __restrict__ Wz,
    const float* __restrict__ x, const float* __restrict__ Cz,
    const float* __restrict__ y, const float* __restrict__ coef,
    float* __restrict__ xc0_mux,     // in: xc0, out: mu_x (same slot)
    float* __restrict__ yc0_muy,     // in: yc0, out: mu_y (same slot)
    float* __restrict__ outW, float* __restrict__ outP, float* __restrict__ outC)
{
    __shared__ float cA[NL], cB[NL];
    const int t = threadIdx.x;
    const int b = (int)blockIdx.x;

    if (b < NBEX) {
        if (t < NL) { cA[t] = coef[t]; cB[t] = coef[NL + t]; }   // u1 | t2
        const int c = (b * 128 + t) << 2;
        float4 xc = *(const float4*)(xc0_mux + c);
        float4 xv = *(const float4*)(x + c);
        float4 mu;
        mu.x = xv.x - xc.x; mu.y = xv.y - xc.y;
        mu.z = xv.z - xc.z; mu.w = xv.w - xc.w;
        *(float4*)(xc0_mux + c) = mu;
        __syncthreads();
#pragma unroll 8
        for (int i = 0; i < NL; ++i) {
            size_t off = (size_t)i * NF + c;
            float4 wv = *(const float4*)(Wz + off);
            float4 pv = *(const float4*)(P + off);
            float u1 = cA[i], t2 = cB[i];
            wv.x = fmaf(u1, xc.x, wv.x); wv.y = fmaf(u1, xc.y, wv.y);
            wv.z = fmaf(u1, xc.z, wv.z); wv.w = fmaf(u1, xc.w, wv.w);
            pv.x = fmaf(t2, xc.x, pv.x); pv.y = fmaf(t2, xc.y, pv.y);
            pv.z = fmaf(t2, xc.z, pv.z); pv.w = fmaf(t2, xc.w, pv.w);
            *(float4*)(outW + off) = wv;
            *(float4*)(outP + off) = pv;
            xc.x = fmaf(-t2, pv.x, xc.x); xc.y = fmaf(-t2, pv.y, xc.y);
            xc.z = fmaf(-t2, pv.z, xc.z); xc.w = fmaf(-t2, pv.w, xc.w);
        }
    } else {
        if (t < NL) { cA[t] = coef[NL + t]; cB[t] = coef[2 * NL + t]; }  // t2 | g
        const int c = ((b - NBEX) * 128 + t) << 2;
        float4 yc = *(const float4*)(yc0_muy + c);
        float4 yv = *(const float4*)(y + c);
        float4 mu;
        mu.x = yv.x - yc.x; mu.y = yv.y - yc.y;
        mu.z = yv.z - yc.z; mu.w = yv.w - yc.w;
        *(float4*)(yc0_muy + c) = mu;
        __syncthreads();
#pragma unroll 8
        for (int i = 0; i < NL; ++i) {
            size_t off = (size_t)i * NT + c;
            float4 cv = *(const float4*)(Cz + off);
            float t2 = cA[i], g = cB[i];
            cv.x = fmaf(t2, yc.x, cv.x); cv.y = fmaf(t2, yc.y, cv.y);
            cv.z = fmaf(t2, yc.z, cv.z); cv.w = fmaf(t2, yc.w, cv.w);
            *(float4*)(outC + off) = cv;
            yc.x = fmaf(-g, cv.x, yc.x); yc.y = fmaf(-g, cv.y, yc.y);
            yc.z = fmaf(-g, cv.z, yc.z); yc.w = fmaf(-g, cv.w, yc.w);
        }
    }
}

// ---------------------------------------------------------------------------
extern "C" void kernel_launch(void* const* d_in, const int* in_sizes, int n_in,
                              void* d_out, int out_size, void* d_ws, size_t ws_size,
                              hipStream_t stream)
{
    (void)in_sizes; (void)n_in; (void)out_size; (void)ws_size;

    const float* x    = (const float*)d_in[0];
    const float* y    = (const float*)d_in[1];
    const float* mu_x = (const float*)d_in[2];
    const float* mu_y = (const float*)d_in[3];
    const float* u    = (const float*)d_in[4];
    const float* Wz   = (const float*)d_in[5];
    const float* Cz   = (const float*)d_in[6];
    const float* tss  = (const float*)d_in[7];
    const float* bz   = (const float*)d_in[8];
    const float* P    = (const float*)d_in[9];
    const int*   n    = (const int*)d_in[10];

    float* out = (float*)d_out;
    float* ws  = (float*)d_ws;

    float* xc0   = out + O_MUX;             // stashed in mu_x slot until expand
    float* yc0   = out + O_MUY;
    float* partX = out + O_P;               // scratch inside P_new output region
    float* partY = partX + (size_t)NBX * PSIZE;
    float* mid   = partY + (size_t)NBY * PSIZE;  // 4.43M+268K < 8.39M  OK
    float* finX  = ws + W_FINX;
    float* finY  = ws + W_FINY;
    float* coef  = ws + W_COEF;

    gram_partial<<<NBX + NBY, 256, 0, stream>>>(P, Wz, x, mu_x,
                                                Cz, y, mu_y, n,
                                                partX, xc0, partY, yc0);

    gram_reduceA<<<33 * NMID, 256, 0, stream>>>(partX, mid);
    gram_reduceB<<<66, 256, 0, stream>>>(mid, partY, finX, finY);

    recursion<<<1, 256, 0, stream>>>(finX, finY, u, tss, bz,
                                     out + O_U, out + O_TSS, out + O_BZ, coef);

    expand<<<NBEX + NBEY, 128, 0, stream>>>(P, Wz, x, Cz, y, coef,
                                            xc0, yc0,
                                            out + O_WZ, out + O_P, out + O_CZ);
}